// Round 6
// baseline (358.484 us; speedup 1.0000x reference)
//
#include <hip/hip_runtime.h>
#include <math.h>

#define CG   32
#define H    1024
#define NBG  512
#define CHN  8            // channels staged per chunk
#define BROW (H + 2)      // zero-padded row
#define EPSV 1e-5f
#define THRV 0.5f

__global__ __launch_bounds__(1024, 4)
void emaru_kernel(const float* __restrict__ x,  const float* __restrict__ w1,
                  const float* __restrict__ b1, const float* __restrict__ w3,
                  const float* __restrict__ b3, const float* __restrict__ gamma,
                  const float* __restrict__ beta, float* __restrict__ out)
{
    // static LDS, total ~51.9 KB (no dynamic smem, no hipFuncSetAttribute)
    __shared__ float  buf[CHN][BROW];     // 32,832 B staging chunk
    __shared__ float  w1s[1024];          //  4,096 B
    __shared__ float  w3s[3072];          // 12,288 B : w3s[(o*CG+i)*3+kh] = w3[o,i,kh,1]
    __shared__ double redP[CG][2];        //    512 B per-channel wave partials (sum)
    __shared__ double redQ[CG][2];        //    512 B (sum of squares)
    __shared__ float  sigwS[CG], x11S[CG], x21S[CG], As[CG], Bs[CG], Cs[CG],
                      muS[CG], rsgS[CG], b1S[CG], b3S[CG], betaS[CG],
                      g0S[CG], gNS[CG];   //  1,664 B

    const int t  = threadIdx.x;           // h position
    const int bg = blockIdx.x;
    const long base = (long)bg * (CG * H);
    const int wid = t >> 6, lane = t & 63;

    // ---- P1: stage params + load column into registers ----
    w1s[t] = w1[t];
    #pragma unroll
    for (int r = 0; r < 3; ++r) w3s[r*1024 + t] = w3[(r*1024 + t)*3 + 1];
    if (t < CG) { b1S[t] = b1[t]; b3S[t] = b3[t]; betaS[t] = beta[t]; }

    float g[CG], gated[CG];
    #pragma unroll
    for (int c = 0; c < CG; ++c) g[c] = x[base + c*H + t];
    if (t == 0) {
        #pragma unroll
        for (int c = 0; c < CG; ++c) g0S[c] = g[c];
    }
    if (t == H-1) {
        #pragma unroll
        for (int c = 0; c < CG; ++c) gNS[c] = g[c];
    }
    __syncthreads();

    // ---- P2a: x11 = softmax(beta)  (exact: mean_h(x1) = beta);  A,B,C[i] = sum_o x11[o]*w3[o,i,kh,1]
    if (t < CG) {
        float m = betaS[0];
        #pragma unroll
        for (int i = 1; i < CG; ++i) m = fmaxf(m, betaS[i]);
        float s = 0.f;
        #pragma unroll
        for (int i = 0; i < CG; ++i) s += expf(betaS[i] - m);
        const float inv = 1.f / s;
        x11S[t] = expf(betaS[t] - m) * inv;
        float a = 0.f, b = 0.f, c = 0.f;
        #pragma unroll
        for (int o = 0; o < CG; ++o) {
            const float f = expf(betaS[o] - m) * inv;
            a = fmaf(f, w3s[(o*CG + t)*3 + 0], a);
            b = fmaf(f, w3s[(o*CG + t)*3 + 1], b);
            c = fmaf(f, w3s[(o*CG + t)*3 + 2], c);
        }
        As[t] = a; Bs[t] = b; Cs[t] = c;
    }

    // ---- P2b: chunked: per-channel sums of gx (f64) + x11-weighted conv dot cd ----
    float cd = 0.f;                       // sum_o x11[o] * x2[o,t]  (bias added later)
    #pragma unroll
    for (int ch = 0; ch < CG/CHN; ++ch) {
        __syncthreads();                  // buf free; iter0: As/Bs/Cs visible
        #pragma unroll
        for (int i = 0; i < CHN; ++i) buf[i][1 + t] = g[ch*CHN + i];
        if (t < CHN) { buf[t][0] = 0.f; buf[t][1 + H] = 0.f; }
        __syncthreads();
        {   // 2 waves per channel, 512 positions each, f64 accumulate
            const int cl = wid >> 1, half = wid & 1;
            const int pos = half*512 + lane;
            double acc = 0.0;
            #pragma unroll
            for (int k = 0; k < 8; ++k) acc += (double)buf[cl][1 + pos + (k << 6)];
            #pragma unroll
            for (int off = 32; off; off >>= 1) acc += __shfl_down(acc, off);
            if (lane == 0) redP[ch*CHN + cl][half] = acc;
        }
        #pragma unroll
        for (int i = 0; i < CHN; ++i) {
            const int gi = ch*CHN + i;
            cd = fmaf(As[gi], buf[i][t],     cd);   // gx[i,t-1] (zero pad)
            cd = fmaf(Bs[gi], g[gi],         cd);   // gx[i,t]
            cd = fmaf(Cs[gi], buf[i][2 + t], cd);   // gx[i,t+1] (zero pad)
        }
    }
    __syncthreads();                       // redP complete, buf reads done

    // ---- P3: sigw[o] (h-mean gate) and x21 = softmax_o(mean_h x2[o]) ----
    if (wid == 0 && lane < CG) {
        const int o = lane;
        float acc = b1S[o];
        for (int i = 0; i < CG; ++i) {
            const float mi = (float)((redP[i][0] + redP[i][1]) * (1.0/H));
            acc = fmaf(w1s[o*CG + i], mi, acc);
        }
        sigwS[o] = 1.f / (1.f + expf(-acc));
    } else if (wid == 1 && lane < CG) {
        const int o = lane;
        double m2 = 0.0;
        for (int i = 0; i < CG; ++i) {
            const double Si = redP[i][0] + redP[i][1];
            m2 += (double)w3s[(o*CG + i)*3 + 0] * (Si - (double)gNS[i])
                + (double)w3s[(o*CG + i)*3 + 1] * Si
                + (double)w3s[(o*CG + i)*3 + 2] * (Si - (double)g0S[i]);
        }
        float mv = (float)(m2 * (1.0/H)) + b3S[o];
        float mx = mv;
        #pragma unroll
        for (int off = 16; off; off >>= 1) mx = fmaxf(mx, __shfl_xor(mx, off));
        const float e = expf(mv - mx);
        float se = e;
        #pragma unroll
        for (int off = 16; off; off >>= 1) se += __shfl_xor(se, off);
        x21S[o] = e / se;
    }
    __syncthreads();

    // ---- P4: gate matvec -> gated;  cd bias ----
    #pragma unroll
    for (int o = 0; o < CG; ++o) {
        float acc = b1S[o];
        #pragma unroll
        for (int i4 = 0; i4 < CG/4; ++i4) {
            const float4 wv = *reinterpret_cast<const float4*>(&w1s[o*CG + i4*4]);
            acc = fmaf(wv.x, g[i4*4+0], acc);
            acc = fmaf(wv.y, g[i4*4+1], acc);
            acc = fmaf(wv.z, g[i4*4+2], acc);
            acc = fmaf(wv.w, g[i4*4+3], acc);
        }
        gated[o] = g[o] * (1.f / (1.f + expf(-acc))) * sigwS[o];
    }
    #pragma unroll
    for (int o = 0; o < CG; ++o) cd = fmaf(x11S[o], b3S[o], cd);

    // ---- P5: chunked mu / var of gated (f64) ----
    #pragma unroll
    for (int ch = 0; ch < CG/CHN; ++ch) {
        __syncthreads();
        #pragma unroll
        for (int i = 0; i < CHN; ++i) buf[i][1 + t] = gated[ch*CHN + i];
        __syncthreads();
        const int cl = wid >> 1, half = wid & 1;
        const int pos = half*512 + lane;
        double sg = 0.0, sq = 0.0;
        #pragma unroll
        for (int k = 0; k < 8; ++k) {
            const double v = (double)buf[cl][1 + pos + (k << 6)];
            sg += v; sq = fma(v, v, sq);
        }
        #pragma unroll
        for (int off = 32; off; off >>= 1) { sg += __shfl_down(sg, off); sq += __shfl_down(sq, off); }
        if (lane == 0) { redP[ch*CHN + cl][half] = sg; redQ[ch*CHN + cl][half] = sq; }
    }
    __syncthreads();
    if (t < CG) {
        const double sg = redP[t][0] + redP[t][1];
        const double sq = redQ[t][0] + redQ[t][1];
        const double mu  = sg * (1.0/H);
        const double var = sq * (1.0/H) - mu*mu;
        muS[t]  = (float)mu;
        rsgS[t] = (float)(1.0 / sqrt(var + (double)EPSV)) * gamma[t];
    }
    __syncthreads();

    // ---- P6: weights, gate, channel-swap routing, store ----
    float wsum = cd;
    #pragma unroll
    for (int o = 0; o < CG; ++o) {
        const float x1o = fmaf(gated[o] - muS[o], rsgS[o], betaS[o]);
        wsum = fmaf(x21S[o], x1o, wsum);
    }
    const float s = 1.f / (1.f + expf(-wsum));
    #pragma unroll
    for (int o = 0; o < CG/2; ++o) {
        const float ga = g[o], gb = g[o + CG/2];
        const bool ia = (ga * s) >= THRV;
        const bool ib = (gb * s) >= THRV;
        out[base + o*H + t]          = (ia ? ga : 0.f) + (ib ? 0.f : gb);
        out[base + (o + CG/2)*H + t] = (ib ? gb : 0.f) + (ia ? 0.f : ga);
    }
}

extern "C" void kernel_launch(void* const* d_in, const int* in_sizes, int n_in,
                              void* d_out, int out_size, void* d_ws, size_t ws_size,
                              hipStream_t stream) {
    const float* x     = (const float*)d_in[0];
    const float* w1    = (const float*)d_in[1];
    const float* b1    = (const float*)d_in[2];
    const float* w3    = (const float*)d_in[3];
    const float* b3    = (const float*)d_in[4];
    const float* gamma = (const float*)d_in[5];
    const float* beta  = (const float*)d_in[6];
    float* out = (float*)d_out;
    emaru_kernel<<<NBG, 1024, 0, stream>>>(x, w1, b1, w3, b3, gamma, beta, out);
}